// Round 8
// baseline (344.077 us; speedup 1.0000x reference)
//
#include <hip/hip_runtime.h>
#include <math.h>

// RoI "mod-7" max pooling (JAX reference-exact).
// x: (2, 512, 50, 50) fp32; rois: (R,5) fp32; out: (R, 512, 7, 7) fp32.
//
// == R7 = R3's exact per-item body + PERSISTENT WAVES with a dynamic queue ==
// Evidence: R1 counters showed Occupancy 46% / VALUBusy 27%, and 2x
// instruction-count changes (R2..R6) moved the bench only +-5us -> the kernel
// is dominated by a scheduling drain tail (per-roi work varies 13x), not by
// issue count. Fix the tail: 2048 blocks (8/CU, full 32-wave residency);
// each wave pops (roi, 4-channel-group) items off a global atomic counter
// (d_ws[0], zeroed via hipMemsetAsync on the stream - capture-safe).
//
// Per-item body (== R3): lane = half*32 + dx, 2 register chains -> 4
// channels/item; masked loads (v_cndmask to -inf for dx >= ftw); row count
// wave-uniform scalar branches; 2-shuffle column fold over {j,j+7,j+14,j+21}.

#define CH 512
#define IH 50
#define IW 50
#define PLANE (IH * IW)
#define NEG_INF (-__builtin_inff())
#define NITEMS (128 * 128)   // 128 rois x 128 four-channel groups

__global__ __launch_bounds__(256) void roipool_kernel(
    const float* __restrict__ x, const float* __restrict__ rois,
    float* __restrict__ out, unsigned* __restrict__ ctr) {
  const int lane = threadIdx.x & 63;
  const int half = lane >> 5;
  const int dx   = lane & 31;          // window column slot (ftw <= 26)

  for (;;) {
    // One lane grabs the next work item; broadcast wave-uniform.
    unsigned it = 0;
    if (lane == 0) it = atomicAdd(ctr, 1u);
    it = __builtin_amdgcn_readfirstlane(it);
    if (it >= NITEMS) break;

    const int r   = it >> 7;        // roi
    const int cgw = it & 127;       // 4-channel group

    // roi decode, forced wave-uniform (SGPRs -> scalar branches/addrs).
    const float* rr = rois + r * 5;
    const int b  = __builtin_amdgcn_readfirstlane((int)rr[0]);
    const int y1 = __builtin_amdgcn_readfirstlane((int)rintf(rr[1] * 0.0625f));
    const int x1 = __builtin_amdgcn_readfirstlane((int)rintf(rr[2] * 0.0625f));
    const int y2 = __builtin_amdgcn_readfirstlane(min((int)rintf(rr[3] * 0.0625f), IH - 1));
    const int x2 = __builtin_amdgcn_readfirstlane(min((int)rintf(rr[4] * 0.0625f), IW - 1));
    const int fth  = y2 - y1 + 1;   // <= 26
    const int ftw  = x2 - x1 + 1;   // <= 26
    const int remh = fth % 7;
    const int remw = ftw % 7;
    const int full = fth / 7;       // 0..3

    const int cbase = cgw * 4 + half * 2;      // channels cbase, cbase+1
    const bool colok = dx < ftw;

    const float* b0 = x + (size_t)(b * CH + cbase) * PLANE + (y1 * IW + x1) + dx;
    const float* b1 = b0 + PLANE;

    float acc0[7], acc1[7];
#pragma unroll
    for (int i = 0; i < 7; ++i) { acc0[i] = NEG_INF; acc1[i] = NEG_INF; }

    // Full super-rows: 14 independent loads per iteration.
    for (int s = 0; s < full; ++s) {
      const int off = s * 7 * IW;
#pragma unroll
      for (int i = 0; i < 7; ++i) {
        float v0 = colok ? b0[off + i * IW] : NEG_INF;  // exec-masked load
        float v1 = colok ? b1[off + i * IW] : NEG_INF;
        acc0[i] = fmaxf(acc0[i], v0);
        acc1[i] = fmaxf(acc1[i], v1);
      }
    }
    // Tail rows (0..6, wave-uniform count -> scalar skip branches).
    {
      const int toff = full * 7 * IW;
#pragma unroll
      for (int i = 0; i < 7; ++i) {
        if (i < remh) {
          float v0 = colok ? b0[toff + i * IW] : NEG_INF;
          float v1 = colok ? b1[toff + i * IW] : NEG_INF;
          acc0[i] = fmaxf(acc0[i], v0);
          acc1[i] = fmaxf(acc1[i], v1);
        }
      }
    }

    // Column fold: lane j (<7 per half) <- max over {j, j+7, j+14, j+21}.
#pragma unroll
    for (int i = 0; i < 7; ++i) {
      float a0 = acc0[i], a1 = acc1[i];
      a0 = fmaxf(a0, __shfl_down(a0, 7, 64));
      a1 = fmaxf(a1, __shfl_down(a1, 7, 64));
      a0 = fmaxf(a0, __shfl_down(a0, 14, 64));
      a1 = fmaxf(a1, __shfl_down(a1, 14, 64));
      acc0[i] = a0;
      acc1[i] = a1;
    }

    // Pad-clamp (bins beyond remh/remw -> max(val, 0)) + store.
    if (dx < 7) {
      const int j = dx;
      const bool padc = (remw != 0) && (j >= remw);
      float* o0 = out + (size_t)(r * CH + cbase) * 49 + j;
      float* o1 = o0 + 49;
#pragma unroll
      for (int i = 0; i < 7; ++i) {
        float v0 = acc0[i], v1 = acc1[i];
        const bool padr = (remh != 0) && (i >= remh);
        if (padr | padc) { v0 = fmaxf(v0, 0.0f); v1 = fmaxf(v1, 0.0f); }
        o0[i * 7] = v0;
        o1[i * 7] = v1;
      }
    }
  }
}

extern "C" void kernel_launch(void* const* d_in, const int* in_sizes, int n_in,
                              void* d_out, int out_size, void* d_ws, size_t ws_size,
                              hipStream_t stream) {
  const float* x    = (const float*)d_in[0];
  const float* rois = (const float*)d_in[1];
  float* out        = (float*)d_out;
  unsigned* ctr     = (unsigned*)d_ws;

  // Zero the work-queue counter (d_ws is poisoned to 0xAA before each call).
  hipMemsetAsync(ctr, 0, sizeof(unsigned), stream);

  dim3 grid(2048);    // 8 blocks/CU x 256 CUs -> full residency, no dispatch tail
  dim3 block(256);    // 4 waves/block; each wave pops 4-channel items
  roipool_kernel<<<grid, block, 0, stream>>>(x, rois, out, ctr);
}

// Round 9
// 72.075 us; speedup vs baseline: 4.7739x; 4.7739x over previous
//
#include <hip/hip_runtime.h>
#include <math.h>

// RoI "mod-7" max pooling (JAX reference-exact).
// x: (2, 512, 50, 50) fp32; rois: (R,5) fp32; out: (R, 512, 7, 7) fp32.
//
// == R8 = R3 (best: 71.0us) + ONE change: single-round branchless row loads ==
// R3's row loop had a dynamic trip count -> full+1 SERIAL memory rounds per
// wave (load batch -> waitcnt -> fmax -> branch -> next batch). Here all row
// loads are issued in ONE round:
//  - supers = ceil(fth/7) is wave-uniform -> scalar 4-way branch into a
//    fully-unrolled run_fast<S> where all 14*S loads are independent.
//  - row clamp s -> min(s, smax_i), smax_i = (fth-1-i)/7: the clamped load
//    duplicates a SAME-BIN row (exact under max). No row predication.
//  - column addresses always in-bounds via cxs = min(dx, ftw-1); invalid
//    columns replaced by -inf with one cndmask (no exec-mask on loads).
//  - fth < 7 (smax_i would go negative): masked slow path (rare, small rois).
// Everything else (grid(32,R) cg-fastest, 4 ch/wave, fold, epilogue) == R3.

#define CH 512
#define IH 50
#define IW 50
#define PLANE (IH * IW)
#define NEG_INF (-__builtin_inff())

__device__ __forceinline__ int imin(int a, int b) { return a < b ? a : b; }

template <int S>
__device__ __forceinline__ void run_fast(const float* __restrict__ b0,
                                         const float* __restrict__ b1,
                                         const int (&smax)[7], bool colok,
                                         float (&acc0)[7], float (&acc1)[7]) {
#pragma unroll
  for (int s = 0; s < S; ++s) {
#pragma unroll
    for (int i = 0; i < 7; ++i) {
      const int off = (i + 7 * imin(s, smax[i])) * IW;  // scalar, >= 0
      float v0 = b0[off];
      float v1 = b1[off];
      v0 = colok ? v0 : NEG_INF;
      v1 = colok ? v1 : NEG_INF;
      acc0[i] = fmaxf(acc0[i], v0);
      acc1[i] = fmaxf(acc1[i], v1);
    }
  }
}

__global__ __launch_bounds__(256) void roipool_kernel(
    const float* __restrict__ x, const float* __restrict__ rois,
    float* __restrict__ out) {
  const int cg   = blockIdx.x;         // channel group fastest (best measured)
  const int r    = blockIdx.y;         // roi
  const int wave = threadIdx.x >> 6;   // 0..3
  const int lane = threadIdx.x & 63;
  const int half = lane >> 5;
  const int dx   = lane & 31;          // window column slot (ftw <= 26)

  // roi decode, forced wave-uniform (SGPRs -> scalar branches, scalar addrs).
  const float* rr = rois + r * 5;
  const int b  = __builtin_amdgcn_readfirstlane((int)rr[0]);
  const int y1 = __builtin_amdgcn_readfirstlane((int)rintf(rr[1] * 0.0625f));
  const int x1 = __builtin_amdgcn_readfirstlane((int)rintf(rr[2] * 0.0625f));
  const int y2 = __builtin_amdgcn_readfirstlane(min((int)rintf(rr[3] * 0.0625f), IH - 1));
  const int x2 = __builtin_amdgcn_readfirstlane(min((int)rintf(rr[4] * 0.0625f), IW - 1));
  const int fth  = y2 - y1 + 1;   // <= 26
  const int ftw  = x2 - x1 + 1;   // <= 26
  const int remh = fth % 7;
  const int remw = ftw % 7;

  // 4 channels per wave: 2 lane-halves x 2 register chains.
  const int cbase = (cg * 4 + wave) * 4 + half * 2;  // channels cbase, cbase+1

  const bool colok = dx < ftw;
  const int  cxs   = imin(dx, ftw - 1);   // always-in-bounds column

  const float* b0 = x + (size_t)(b * CH + cbase) * PLANE + (y1 * IW + x1) + cxs;
  const float* b1 = b0 + PLANE;

  float acc0[7], acc1[7];
#pragma unroll
  for (int i = 0; i < 7; ++i) { acc0[i] = NEG_INF; acc1[i] = NEG_INF; }

  if (fth >= 7) {
    int smax[7];
#pragma unroll
    for (int i = 0; i < 7; ++i) smax[i] = (fth - 1 - i) / 7;  // 0..3, scalar
    const int supers = (fth + 6) / 7;  // 1..4, wave-uniform
    if      (supers == 1) run_fast<1>(b0, b1, smax, colok, acc0, acc1);
    else if (supers == 2) run_fast<2>(b0, b1, smax, colok, acc0, acc1);
    else if (supers == 3) run_fast<3>(b0, b1, smax, colok, acc0, acc1);
    else                  run_fast<4>(b0, b1, smax, colok, acc0, acc1);
  } else {
    // fth < 7: only bin-rows i < fth have data (scalar skip branches).
#pragma unroll
    for (int i = 0; i < 7; ++i) {
      if (i < fth) {
        float v0 = b0[i * IW];
        float v1 = b1[i * IW];
        v0 = colok ? v0 : NEG_INF;
        v1 = colok ? v1 : NEG_INF;
        acc0[i] = fmaxf(acc0[i], v0);
        acc1[i] = fmaxf(acc1[i], v1);
      }
    }
  }

  // Column fold: lane j (<7 per half) <- max over {j, j+7, j+14, j+21}
  // (col j+28 >= 28 > 26 >= ftw is never valid -> two shuffle steps).
#pragma unroll
  for (int i = 0; i < 7; ++i) {
    float a0 = acc0[i], a1 = acc1[i];
    a0 = fmaxf(a0, __shfl_down(a0, 7, 64));
    a1 = fmaxf(a1, __shfl_down(a1, 7, 64));
    a0 = fmaxf(a0, __shfl_down(a0, 14, 64));
    a1 = fmaxf(a1, __shfl_down(a1, 14, 64));
    acc0[i] = a0;
    acc1[i] = a1;
  }

  // Pad-clamp (bins beyond remh/remw -> max(val, 0)) + store.
  if (dx < 7) {
    const int j = dx;
    const bool padc = (remw != 0) && (j >= remw);
    float* o0 = out + (size_t)(r * CH + cbase) * 49 + j;
    float* o1 = o0 + 49;
#pragma unroll
    for (int i = 0; i < 7; ++i) {
      float v0 = acc0[i], v1 = acc1[i];
      const bool padr = (remh != 0) && (i >= remh);
      if (padr | padc) { v0 = fmaxf(v0, 0.0f); v1 = fmaxf(v1, 0.0f); }
      o0[i * 7] = v0;
      o1[i * 7] = v1;
    }
  }
}

extern "C" void kernel_launch(void* const* d_in, const int* in_sizes, int n_in,
                              void* d_out, int out_size, void* d_ws, size_t ws_size,
                              hipStream_t stream) {
  const float* x    = (const float*)d_in[0];
  const float* rois = (const float*)d_in[1];
  float* out        = (float*)d_out;
  const int R = in_sizes[1] / 5;  // 128

  dim3 grid(32, R);   // cg fastest x roi (best-measured ordering)
  dim3 block(256);    // 4 waves; each wave = 4 channels
  roipool_kernel<<<grid, block, 0, stream>>>(x, rois, out);
}